// Round 4
// baseline (752.001 us; speedup 1.0000x reference)
//
#include <hip/hip_runtime.h>

// FastHelgasonMLP: out = x @ (U diag(S) V^T)^T, factored:
//   t[16384,1024] = xb @ VsT^T ;  out[16384,4096] = t @ Ub^T
// R4: persistent n-group blocks (NJ template param). GEMM2 runs 256 blocks
// (1/CU), each covering 4 n-tiles of one m-panel; at sub-gemm seams the
// C-stores of tile j overlap the prologue staging of tile j+1 (stores issued
// first so the seam vmcnt(6) covers stores + tile0 loads). Removes 3 of 4
// fill/drain/write serializations per CU. GEMM1: NJ=1 (identical to R3).
// 256x256 8-phase GEMM (T2 swizzle + T3/T4 counted-vmcnt + T5 setprio).

typedef __bf16 bf16;
typedef __bf16 bf16x4 __attribute__((ext_vector_type(4)));
typedef __bf16 bf16x8 __attribute__((ext_vector_type(8)));
typedef float  f32x4  __attribute__((ext_vector_type(4)));

#define M_DIM   16384
#define IN_DIM  4096
#define OUT_DIM 4096
#define RK_DIM  1024

// ---------------------------------------------------------------------------
// Prep (unchanged): cast x->bf16, U->bf16, build VsT[r][i] = V[i][r]*S[r].
// ---------------------------------------------------------------------------
__global__ __launch_bounds__(256)
void prep_kernel(const float* __restrict__ x, const float* __restrict__ U,
                 const float* __restrict__ S, const float* __restrict__ V,
                 bf16* __restrict__ xb, bf16* __restrict__ Ub,
                 bf16* __restrict__ VsT, int xblocks)
{
    __shared__ float tile[64][68];
    const int b = blockIdx.x;
    const int tid = threadIdx.x;

    if (b < xblocks) {
        const float4* xin = (const float4*)x;
        size_t base = (size_t)b * 2048 + tid;
        #pragma unroll
        for (int i = 0; i < 8; ++i) {
            float4 v = xin[base + (size_t)i * 256];
            bf16x4 o = { (bf16)v.x, (bf16)v.y, (bf16)v.z, (bf16)v.w };
            *(bf16x4*)&xb[(base + (size_t)i * 256) * 4] = o;
        }
    } else if (b < xblocks + 512) {
        const float4* uin = (const float4*)U;
        size_t base = (size_t)(b - xblocks) * 2048 + tid;
        #pragma unroll
        for (int i = 0; i < 8; ++i) {
            float4 v = uin[base + (size_t)i * 256];
            bf16x4 o = { (bf16)v.x, (bf16)v.y, (bf16)v.z, (bf16)v.w };
            *(bf16x4*)&Ub[(base + (size_t)i * 256) * 4] = o;
        }
    } else {
        const int vb   = b - (xblocks + 512);
        const int rblk = vb & 15;
        const int iblk = vb >> 4;
        const int r0 = rblk * 64, i0 = iblk * 64;

        const int tr  = tid >> 4;
        const int tc4 = (tid & 15) * 4;
        #pragma unroll
        for (int j = 0; j < 4; ++j) {
            float4 v = *(const float4*)&V[(size_t)(i0 + tr + j * 16) * RK_DIM + r0 + tc4];
            tile[tr + j * 16][tc4 + 0] = v.x;
            tile[tr + j * 16][tc4 + 1] = v.y;
            tile[tr + j * 16][tc4 + 2] = v.z;
            tile[tr + j * 16][tc4 + 3] = v.w;
        }
        __syncthreads();
        const int rr  = tid >> 2;
        const int ic0 = (tid & 3) * 16;
        const float s = S[r0 + rr];
        #pragma unroll
        for (int j = 0; j < 4; ++j) {
            bf16x4 o;
            #pragma unroll
            for (int q = 0; q < 4; ++q)
                o[q] = (bf16)(tile[ic0 + j * 4 + q][rr] * s);
            *(bf16x4*)&VsT[(size_t)(r0 + rr) * IN_DIM + i0 + ic0 + j * 4] = o;
        }
    }
}

__device__ __forceinline__ void gload16(const bf16* g, bf16* l)
{
    __builtin_amdgcn_global_load_lds(
        (const __attribute__((address_space(1))) void*)g,
        (__attribute__((address_space(3))) void*)l,
        16, 0, 0);
}

// ---------------------------------------------------------------------------
// gemm_bt_8p<CT,NJ>: C[M,N] = A[M,K]*B[N,K]^T, bf16 in, fp32 acc, CT out.
// 512 thr = 8 waves (2 wrow x 4 wcol), tile 256x256, BK=64, NT=K/64 tiles.
// Block bx owns NJ consecutive n-tiles (persistent A-panel); grid.x = N/256/NJ.
// LDS: [buf2][op2][half2][128x64] bf16 = 128 KiB, double-buffered.
// Seam (j>0): WRITE_C(j-1) stores -> PROLOGUE(j) gloads -> acc reset ->
// vmcnt(6) (stores are oldest: wait = all stores + 8 loads = tile0 ready).
// ---------------------------------------------------------------------------
template <typename CT, int NJ>
__global__ __launch_bounds__(512)
void gemm_bt_8p(const bf16* __restrict__ A, const bf16* __restrict__ B,
                CT* __restrict__ C, int M, int N, int K)
{
    __shared__ bf16 lds[2][2][2][8192];   // [buf][A/B][half][128*64]

    const int tid  = threadIdx.x;
    const int lane = tid & 63;
    const int wave = tid >> 6;       // 0..7
    const int wrow = wave >> 2;      // 0..1  (128-row half of C)
    const int wcol = wave & 3;       // 0..3  (64-col strip of C)

    // ---- XCD-aware bijective remap (panel-co-location) ----
    int bx = blockIdx.x, by = blockIdx.y;
    {
        const int ncols = gridDim.x;
        const int total = ncols * gridDim.y;
        if ((total & 7) == 0) {
            const int h   = by * ncols + bx;     // hardware dispatch order
            const int per = total >> 3;          // works per XCD
            const int w   = (h & 7) * per + (h >> 3);
            by = w / ncols;
            bx = w - by * ncols;
        }
    }
    const int m0 = by * 256;
    const int NT = K >> 6;

    // --- staging constants ---
    const int srow8  = lane >> 3;
    const int colswz = ((lane & 7) * 8) ^ (((lane >> 4) & 1) * 8)
                                        ^ (((lane >> 5) & 1) * 16);

    // --- fragment-read constants ---
    const int fr   = lane & 15;
    const int kq2  = (lane >> 4) * 16;                    // bytes
    const int x45  = (fr & 6) << 3;
    const int x6   = (fr & 8) << 3;
    const int koffe[2] = { ((kq2 ^ x45) + (0  ^ x6)) >> 1,
                           ((kq2 ^ x45) + (64 ^ x6)) >> 1 };   // bf16 elts

    f32x4 acc[8][4];
    #pragma unroll
    for (int mi = 0; mi < 8; ++mi)
        #pragma unroll
        for (int ni = 0; ni < 4; ++ni)
            acc[mi][ni] = (f32x4){0.f, 0.f, 0.f, 0.f};

    auto STAGE = [&](const bf16* __restrict__ G, int g0, int tile, int op, int half) {
        bf16* dst = &lds[tile & 1][op][half][wave * 1024];
        #pragma unroll
        for (int i = 0; i < 2; ++i) {
            const int row = g0 + half * 128 + wave * 16 + i * 8 + srow8;
            const bf16* src = G + (size_t)row * K + tile * 64 + (colswz ^ (i * 32));
            gload16(src, dst + i * 512);
        }
    };

    auto PROLOGUE = [&](int n0) {
        STAGE(A, m0, 0, 0, 0); STAGE(A, m0, 0, 0, 1);
        STAGE(B, n0, 0, 1, 0); STAGE(B, n0, 0, 1, 1);
        if (NT > 1) {
            STAGE(A, m0, 1, 0, 0); STAGE(A, m0, 1, 0, 1); STAGE(B, n0, 1, 1, 0);
        }
    };

    auto WRITE_C = [&](int n0) {
        // C/D layout col=lane&15, row=(lane>>4)*4+reg (m89/m91)
        const int ccol  = n0 + wcol * 64 + fr;
        const int crow0 = m0 + wrow * 128 + (lane >> 4) * 4;
        #pragma unroll
        for (int mi = 0; mi < 8; ++mi)
            #pragma unroll
            for (int ni = 0; ni < 4; ++ni)
                #pragma unroll
                for (int r = 0; r < 4; ++r)
                    C[(size_t)(crow0 + mi * 16 + r) * N + ccol + ni * 16] =
                        (CT)acc[mi][ni][r];
    };

    bf16x8 af[4][2], bv[4][2];

    for (int j = 0; j < NJ; ++j) {
        const int n0 = (bx * NJ + j) * 256;

        if (j == 0) {
            PROLOGUE(n0);
        } else {
            // seam: stores of sub-gemm j-1 overlap prologue of sub-gemm j.
            // (previous K-loop drained vmcnt to 0 at its t=NT-2 boundary and
            // its final barrier retired all LDS reads -> DMA-safe.)
            WRITE_C(n0 - 256);
            PROLOGUE(n0);
            #pragma unroll
            for (int mi = 0; mi < 8; ++mi)
                #pragma unroll
                for (int ni = 0; ni < 4; ++ni)
                    acc[mi][ni] = (f32x4){0.f, 0.f, 0.f, 0.f};
        }
        if (NT > 1)
            asm volatile("s_waitcnt vmcnt(6)" ::: "memory");
        else
            asm volatile("s_waitcnt vmcnt(0)" ::: "memory");
        __builtin_amdgcn_s_barrier();

        for (int t = 0; t < NT; ++t) {
            const int cbuf = t & 1;
            const bf16* aB = &lds[cbuf][0][wrow][fr * 64];
            const bf16* bB = &lds[cbuf][1][wcol >> 1][(wcol & 1) * 4096 + fr * 64];

            // ============= phase 1: read A(mi0-3)+B(ni0-1), MFMA q1 ========
            #pragma unroll
            for (int q = 0; q < 4; ++q)
                #pragma unroll
                for (int h = 0; h < 2; ++h)
                    af[q][h] = *(const bf16x8*)(aB + q * 1024 + koffe[h]);
            #pragma unroll
            for (int n = 0; n < 2; ++n)
                #pragma unroll
                for (int h = 0; h < 2; ++h)
                    bv[n][h] = *(const bf16x8*)(bB + n * 1024 + koffe[h]);
            if (t + 1 < NT) STAGE(B, n0, t + 1, 1, 1);
            __builtin_amdgcn_s_barrier();
            asm volatile("s_waitcnt lgkmcnt(0)" ::: "memory");
            __builtin_amdgcn_sched_barrier(0);
            __builtin_amdgcn_s_setprio(1);
            #pragma unroll
            for (int q = 0; q < 4; ++q)
                #pragma unroll
                for (int n = 0; n < 2; ++n)
                    #pragma unroll
                    for (int h = 0; h < 2; ++h)
                        acc[q][n] = __builtin_amdgcn_mfma_f32_16x16x32_bf16(
                            af[q][h], bv[n][h], acc[q][n], 0, 0, 0);
            __builtin_amdgcn_s_setprio(0);
            __builtin_amdgcn_s_barrier();

            // ============= phase 2: read B(ni2-3), MFMA q2 =================
            #pragma unroll
            for (int n = 2; n < 4; ++n)
                #pragma unroll
                for (int h = 0; h < 2; ++h)
                    bv[n][h] = *(const bf16x8*)(bB + n * 1024 + koffe[h]);
            __builtin_amdgcn_s_barrier();
            asm volatile("s_waitcnt lgkmcnt(0)" ::: "memory");
            __builtin_amdgcn_sched_barrier(0);
            __builtin_amdgcn_s_setprio(1);
            #pragma unroll
            for (int q = 0; q < 4; ++q)
                #pragma unroll
                for (int n = 2; n < 4; ++n)
                    #pragma unroll
                    for (int h = 0; h < 2; ++h)
                        acc[q][n] = __builtin_amdgcn_mfma_f32_16x16x32_bf16(
                            af[q][h], bv[n][h], acc[q][n], 0, 0, 0);
            __builtin_amdgcn_s_setprio(0);
            __builtin_amdgcn_s_barrier();

            // ============= phase 3: read A(mi4-7), MFMA q3 =================
            #pragma unroll
            for (int q = 0; q < 4; ++q)
                #pragma unroll
                for (int h = 0; h < 2; ++h)
                    af[q][h] = *(const bf16x8*)(aB + (4 + q) * 1024 + koffe[h]);
            if (t + 2 < NT) STAGE(B, n0, t + 2, 1, 0);   // B reads retired at p2 barrier
            __builtin_amdgcn_s_barrier();
            asm volatile("s_waitcnt lgkmcnt(0)" ::: "memory");
            __builtin_amdgcn_sched_barrier(0);
            __builtin_amdgcn_s_setprio(1);
            #pragma unroll
            for (int q = 0; q < 4; ++q)
                #pragma unroll
                for (int n = 2; n < 4; ++n)
                    #pragma unroll
                    for (int h = 0; h < 2; ++h)
                        acc[4 + q][n] = __builtin_amdgcn_mfma_f32_16x16x32_bf16(
                            af[q][h], bv[n][h], acc[4 + q][n], 0, 0, 0);
            __builtin_amdgcn_s_setprio(0);
            __builtin_amdgcn_s_barrier();

            // ============= phase 4: MFMA q4, stage A(t+2), boundary vmcnt ==
            if (t + 2 < NT) {                             // A reads retired at p3 barrier
                STAGE(A, m0, t + 2, 0, 0);
                STAGE(A, m0, t + 2, 0, 1);
            }
            __builtin_amdgcn_s_barrier();
            asm volatile("s_waitcnt lgkmcnt(0)" ::: "memory");
            __builtin_amdgcn_sched_barrier(0);
            __builtin_amdgcn_s_setprio(1);
            #pragma unroll
            for (int q = 0; q < 4; ++q)
                #pragma unroll
                for (int n = 0; n < 2; ++n)
                    #pragma unroll
                    for (int h = 0; h < 2; ++h)
                        acc[4 + q][n] = __builtin_amdgcn_mfma_f32_16x16x32_bf16(
                            af[q][h], bv[n][h], acc[4 + q][n], 0, 0, 0);
            __builtin_amdgcn_s_setprio(0);
            if (t + 2 < NT)
                asm volatile("s_waitcnt vmcnt(6)" ::: "memory");  // 3 half-tiles in flight
            else if (t + 1 < NT)
                asm volatile("s_waitcnt vmcnt(0)" ::: "memory");  // drain for last tile
            __builtin_amdgcn_s_barrier();
        }
    }

    WRITE_C((bx * NJ + NJ - 1) * 256);
}

// ---------------------------------------------------------------------------
// Fallback GEMM1 (fp32 A, register staging, 128^2) — only if ws too small.
// ---------------------------------------------------------------------------
__global__ __launch_bounds__(256)
void gemm_bt_f32a(const float* __restrict__ A, const bf16* __restrict__ B,
                  bf16* __restrict__ C, int M, int N, int K)
{
    __shared__ bf16 As[128][40];
    __shared__ bf16 Bs[128][40];

    const int tid  = threadIdx.x;
    const int lane = tid & 63;
    const int wave = tid >> 6;
    const int wrow = wave >> 1;
    const int wcol = wave & 1;
    const int n0 = blockIdx.x * 128;
    const int m0 = blockIdx.y * 128;

    f32x4 acc[4][4];
    #pragma unroll
    for (int mi = 0; mi < 4; ++mi)
        #pragma unroll
        for (int ni = 0; ni < 4; ++ni)
            acc[mi][ni] = (f32x4){0.f, 0.f, 0.f, 0.f};

    const int fr = lane & 15;
    const int kq = (lane >> 4) * 8;

    for (int kk = 0; kk < K; kk += 32) {
        __syncthreads();
        #pragma unroll
        for (int i = 0; i < 4; ++i) {
            int c = tid + i * 256;
            int row = c >> 3, kc = (c & 7) * 4;
            float4 v = *(const float4*)&A[(size_t)(m0 + row) * K + kk + kc];
            bf16x4 o = { (bf16)v.x, (bf16)v.y, (bf16)v.z, (bf16)v.w };
            *(bf16x4*)&As[row][kc] = o;
        }
        #pragma unroll
        for (int i = 0; i < 2; ++i) {
            int c = tid + i * 256;
            int row = c >> 2, kc = (c & 3) * 8;
            *(bf16x8*)&Bs[row][kc] = *(const bf16x8*)&B[(size_t)(n0 + row) * K + kk + kc];
        }
        __syncthreads();

        bf16x8 af[4], bfg[4];
        #pragma unroll
        for (int i = 0; i < 4; ++i) {
            af[i]  = *(const bf16x8*)&As[wrow * 64 + i * 16 + fr][kq];
            bfg[i] = *(const bf16x8*)&Bs[wcol * 64 + i * 16 + fr][kq];
        }
        #pragma unroll
        for (int mi = 0; mi < 4; ++mi)
            #pragma unroll
            for (int ni = 0; ni < 4; ++ni)
                acc[mi][ni] = __builtin_amdgcn_mfma_f32_16x16x32_bf16(
                    af[mi], bfg[ni], acc[mi][ni], 0, 0, 0);
    }

    const int ccol  = n0 + wcol * 64 + fr;
    const int crow0 = m0 + wrow * 64 + (lane >> 4) * 4;
    #pragma unroll
    for (int mi = 0; mi < 4; ++mi)
        #pragma unroll
        for (int ni = 0; ni < 4; ++ni)
            #pragma unroll
            for (int r = 0; r < 4; ++r)
                C[(size_t)(crow0 + mi * 16 + r) * N + ccol + ni * 16] =
                    (bf16)acc[mi][ni][r];
}

// ---------------------------------------------------------------------------
extern "C" void kernel_launch(void* const* d_in, const int* in_sizes, int n_in,
                              void* d_out, int out_size, void* d_ws, size_t ws_size,
                              hipStream_t stream)
{
    const float* x = (const float*)d_in[0];
    const float* U = (const float*)d_in[1];
    const float* S = (const float*)d_in[2];
    const float* V = (const float*)d_in[3];
    float* out = (float*)d_out;

    const size_t SZ_XB  = (size_t)M_DIM * IN_DIM * 2;
    const size_t SZ_UB  = (size_t)OUT_DIM * RK_DIM * 2;
    const size_t SZ_VST = (size_t)RK_DIM * IN_DIM * 2;
    const size_t SZ_T   = (size_t)M_DIM * RK_DIM * 2;

    char* p = (char*)d_ws;
    const bool full = ws_size >= SZ_XB + SZ_UB + SZ_VST + SZ_T;
    bf16* xb = nullptr;
    if (full) { xb = (bf16*)p; p += SZ_XB; }
    bf16* Ub  = (bf16*)p; p += SZ_UB;
    bf16* VsT = (bf16*)p; p += SZ_VST;
    bf16* t   = (bf16*)p;

    const int xblocks = full ? 8192 : 0;
    prep_kernel<<<xblocks + 512 + 1024, 256, 0, stream>>>(
        x, U, S, V, full ? xb : Ub, Ub, VsT, xblocks);

    // GEMM1: t[M, RK] = xb[M, IN] * VsT[RK, IN]^T  (NJ=1, grid 4x64 = 256)
    if (full)
        gemm_bt_8p<bf16, 1><<<dim3(RK_DIM / 256, M_DIM / 256), 512, 0, stream>>>(
            xb, VsT, t, M_DIM, RK_DIM, IN_DIM);
    else
        gemm_bt_f32a<<<dim3(RK_DIM / 128, M_DIM / 128), 256, 0, stream>>>(
            x, VsT, t, M_DIM, RK_DIM, IN_DIM);

    // GEMM2: out[M, OUT] = t[M, RK] * Ub[OUT, RK]^T  (NJ=4, grid 4x64 = 256)
    gemm_bt_8p<float, 4><<<dim3(OUT_DIM / 256 / 4, M_DIM / 256), 512, 0, stream>>>(
        t, Ub, out, M_DIM, OUT_DIM, RK_DIM);
}